// Round 1
// baseline (536.010 us; speedup 1.0000x reference)
//
#include <hip/hip_runtime.h>
#include <hip/hip_bf16.h>
#include <hip/hip_fp16.h>

// ---------- common types ----------
typedef __attribute__((ext_vector_type(8))) short bf16x8;   // 8 bf16 = 4 VGPR (MFMA A/B frag)
typedef __attribute__((ext_vector_type(4))) float f32x4;    // MFMA C/D frag

__device__ __forceinline__ short f2bf(float x) {
    unsigned u = __builtin_bit_cast(unsigned, x);
    u += 0x7fffu + ((u >> 16) & 1u);          // RNE
    return (short)(u >> 16);
}

// ---------- K0: f32 -> bf16 convert (vectorized x4) ----------
__global__ void convert_f32_bf16(const float* __restrict__ src, short* __restrict__ dst, int n4) {
    int i = blockIdx.x * blockDim.x + threadIdx.x;
    if (i < n4) {
        float4 v = reinterpret_cast<const float4*>(src)[i];
        short4 o;
        o.x = f2bf(v.x); o.y = f2bf(v.y); o.z = f2bf(v.z); o.w = f2bf(v.w);
        reinterpret_cast<short4*>(dst)[i] = o;
    }
}

// ---------- K1: geometry bias  g_log[b][h][n][m] (f16) ----------
// thread = one (n,m) pair, all 16 heads. sin/cos computed once per pair.
__global__ void geom_kernel(const float* __restrict__ boxes, const float* __restrict__ Wg,
                            const float* __restrict__ bg, __half* __restrict__ GL) {
    const int m = blockIdx.x * 256 + threadIdx.x;   // key index
    const int n = blockIdx.y;                       // query index
    const int b = blockIdx.z;

    // query box (wave-uniform -> scalar loads)
    float4 bn = reinterpret_cast<const float4*>(boxes)[b * 512 + n];
    float cxn = (bn.x + bn.z) * 0.5f, cyn = (bn.y + bn.w) * 0.5f;
    float wn = bn.z - bn.x + 1.0f, hn = bn.w - bn.y + 1.0f;
    // key box (per-lane)
    float4 bm = reinterpret_cast<const float4*>(boxes)[b * 512 + m];
    float cxm = (bm.x + bm.z) * 0.5f, cym = (bm.y + bm.w) * 0.5f;
    float wm = bm.z - bm.x + 1.0f, hm = bm.w - bm.y + 1.0f;

    float pos[4];
    pos[0] = __logf(fmaxf(fabsf((cxn - cxm) / wn), 1e-3f));
    pos[1] = __logf(fmaxf(fabsf((cyn - cym) / hn), 1e-3f));
    pos[2] = __logf(wn / wm);
    pos[3] = __logf(hn / hm);

    const float dm[8] = {1.0f, 0.42169651f, 0.17782794f, 0.07498942f,
                         0.03162278f, 0.01333521f, 0.00562341f, 0.00237137f};
    float sv[32], cv[32];
    #pragma unroll
    for (int c = 0; c < 4; ++c)
        #pragma unroll
        for (int f = 0; f < 8; ++f) {
            float th = 100.0f * pos[c] * dm[f];
            sv[c * 8 + f] = __sinf(th);
            cv[c * 8 + f] = __cosf(th);
        }

    for (int h = 0; h < 16; ++h) {
        float acc = bg[h];
        #pragma unroll
        for (int d = 0; d < 32; ++d)
            acc += Wg[h * 64 + d] * sv[d] + Wg[h * 64 + 32 + d] * cv[d];
        float g = fmaxf(acc, 0.0f);          // relu
        g = fmaxf(g, 1e-6f);                 // clip
        GL[((long)((b * 16 + h) * 512 + n)) * 512 + m] = __float2half(__logf(g));
    }
}

// ---------- K2/K4: GEMM  C[m][n] = sum_k A[m][k] * B[n][k]  (+bias) ----------
// A: MxK row-major bf16, B: NxK row-major bf16. 128x128 workgroup tile,
// 4 waves in 2x2, each wave 64x64 (4x4 C-frags), direct-from-global fragments.
template<bool OUT_F32, bool BIAS_M>
__global__ void gemm_bf16(const short* __restrict__ A, const short* __restrict__ B, long sB,
                          const float* __restrict__ bias, void* __restrict__ Cv, long sC,
                          int K, int ldc) {
    const int tid = threadIdx.x;
    const int wave = tid >> 6, lane = tid & 63, quad = lane >> 4, l16 = lane & 15;
    const int m0 = blockIdx.y * 128 + (wave >> 1) * 64;
    const int n0 = blockIdx.x * 128 + (wave & 1) * 64;
    const short* Bp = B + (long)blockIdx.z * sB;

    f32x4 acc[4][4];
    #pragma unroll
    for (int mg = 0; mg < 4; ++mg)
        #pragma unroll
        for (int ng = 0; ng < 4; ++ng)
            acc[mg][ng] = (f32x4){0.f, 0.f, 0.f, 0.f};

    const short* a_base = A  + (long)(m0 + l16) * K + quad * 8;
    const short* b_base = Bp + (long)(n0 + l16) * K + quad * 8;

    for (int k0 = 0; k0 < K; k0 += 32) {
        bf16x8 a[4], bb[4];
        #pragma unroll
        for (int g = 0; g < 4; ++g) {
            a[g]  = *(const bf16x8*)(a_base + (long)g * 16 * K + k0);
            bb[g] = *(const bf16x8*)(b_base + (long)g * 16 * K + k0);
        }
        #pragma unroll
        for (int mg = 0; mg < 4; ++mg)
            #pragma unroll
            for (int ng = 0; ng < 4; ++ng)
                acc[mg][ng] = __builtin_amdgcn_mfma_f32_16x16x32_bf16(a[mg], bb[ng], acc[mg][ng], 0, 0, 0);
    }

    #pragma unroll
    for (int mg = 0; mg < 4; ++mg)
        #pragma unroll
        for (int ng = 0; ng < 4; ++ng)
            #pragma unroll
            for (int r = 0; r < 4; ++r) {
                int row = m0 + mg * 16 + quad * 4 + r;
                int col = n0 + ng * 16 + l16;
                float v = acc[mg][ng][r] + (BIAS_M ? bias[row] : bias[col]);
                long ci = (long)blockIdx.z * sC + (long)row * ldc + col;
                if constexpr (OUT_F32) ((float*)Cv)[ci] = v;
                else                   ((short*)Cv)[ci] = f2bf(v);
            }
}

// ---------- K3: flash attention with geometric bias ----------
// grid (qt=8, h=16, b=8), 256 threads = 4 waves, each wave 16 q-rows, k-tiles of 64.
__global__ void flash_attn(const short* __restrict__ Q, const short* __restrict__ Kh,
                           const short* __restrict__ Vt, const __half* __restrict__ GL,
                           short* __restrict__ O) {
    const int tid = threadIdx.x;
    const int wave = tid >> 6, lane = tid & 63, quad = lane >> 4, l16 = lane & 15;
    const int qt = blockIdx.x, h = blockIdx.y, b = blockIdx.z;

    __shared__ __align__(16) short Pbuf[4][16][72];   // +8 pad: ds_read_b128 lands 2-way (free)

    const int qrow = qt * 64 + wave * 16;
    const long qoff = ((long)(b * 512 + qrow + l16)) * 1024 + h * 64 + quad * 8;
    bf16x8 aq0 = *(const bf16x8*)(Q + qoff);
    bf16x8 aq1 = *(const bf16x8*)(Q + qoff + 32);

    f32x4 oacc[4];
    float mi[4], li[4];
    #pragma unroll
    for (int r = 0; r < 4; ++r) {
        oacc[r] = (f32x4){0.f, 0.f, 0.f, 0.f};
        mi[r] = -1e30f; li[r] = 0.f;
    }

    for (int kt = 0; kt < 8; ++kt) {
        float lg[4][4];
        #pragma unroll
        for (int nk = 0; nk < 4; ++nk) {
            const long koff = ((long)(b * 512 + kt * 64 + nk * 16 + l16)) * 1024 + h * 64 + quad * 8;
            bf16x8 bk0 = *(const bf16x8*)(Kh + koff);
            bf16x8 bk1 = *(const bf16x8*)(Kh + koff + 32);
            f32x4 s = (f32x4){0.f, 0.f, 0.f, 0.f};
            s = __builtin_amdgcn_mfma_f32_16x16x32_bf16(aq0, bk0, s, 0, 0, 0);
            s = __builtin_amdgcn_mfma_f32_16x16x32_bf16(aq1, bk1, s, 0, 0, 0);
            #pragma unroll
            for (int r = 0; r < 4; ++r) {
                float gl = __half2float(GL[((long)((b * 16 + h) * 512 + qrow + quad * 4 + r)) * 512
                                           + kt * 64 + nk * 16 + l16]);
                lg[nk][r] = s[r] * 0.125f + gl;
            }
        }
        float mnew[4], alpha[4], rs[4];
        #pragma unroll
        for (int r = 0; r < 4; ++r) {
            float mx = fmaxf(fmaxf(lg[0][r], lg[1][r]), fmaxf(lg[2][r], lg[3][r]));
            mx = fmaxf(mx, __shfl_xor(mx, 1));
            mx = fmaxf(mx, __shfl_xor(mx, 2));
            mx = fmaxf(mx, __shfl_xor(mx, 4));
            mx = fmaxf(mx, __shfl_xor(mx, 8));
            mnew[r] = fmaxf(mi[r], mx);
            alpha[r] = __expf(mi[r] - mnew[r]);
            mi[r] = mnew[r];
            rs[r] = 0.f;
        }
        #pragma unroll
        for (int nk = 0; nk < 4; ++nk)
            #pragma unroll
            for (int r = 0; r < 4; ++r) { float p = __expf(lg[nk][r] - mnew[r]); lg[nk][r] = p; rs[r] += p; }
        #pragma unroll
        for (int r = 0; r < 4; ++r) {
            float s4 = rs[r];
            s4 += __shfl_xor(s4, 1); s4 += __shfl_xor(s4, 2);
            s4 += __shfl_xor(s4, 4); s4 += __shfl_xor(s4, 8);
            li[r] = li[r] * alpha[r] + s4;
        }
        #pragma unroll
        for (int n4 = 0; n4 < 4; ++n4)
            #pragma unroll
            for (int r = 0; r < 4; ++r) oacc[n4][r] *= alpha[r];

        __syncthreads();   // protect Pbuf WAR across iterations
        #pragma unroll
        for (int nk = 0; nk < 4; ++nk)
            #pragma unroll
            for (int r = 0; r < 4; ++r)
                Pbuf[wave][quad * 4 + r][nk * 16 + l16] = f2bf(lg[nk][r]);
        __syncthreads();

        // P in A-frag layout from LDS; V from global (Vt is [b][1024][512], K-contiguous)
        bf16x8 ap0 = *(const bf16x8*)&Pbuf[wave][l16][quad * 8];
        bf16x8 ap1 = *(const bf16x8*)&Pbuf[wave][l16][32 + quad * 8];
        #pragma unroll
        for (int n4 = 0; n4 < 4; ++n4) {
            const long voff = ((long)(b * 1024 + h * 64 + n4 * 16 + l16)) * 512 + kt * 64 + quad * 8;
            bf16x8 bv0 = *(const bf16x8*)(Vt + voff);
            bf16x8 bv1 = *(const bf16x8*)(Vt + voff + 32);
            oacc[n4] = __builtin_amdgcn_mfma_f32_16x16x32_bf16(ap0, bv0, oacc[n4], 0, 0, 0);
            oacc[n4] = __builtin_amdgcn_mfma_f32_16x16x32_bf16(ap1, bv1, oacc[n4], 0, 0, 0);
        }
    }

    #pragma unroll
    for (int n4 = 0; n4 < 4; ++n4)
        #pragma unroll
        for (int r = 0; r < 4; ++r) {
            float o = oacc[n4][r] / li[r];
            O[((long)(b * 512 + qrow + quad * 4 + r)) * 1024 + h * 64 + n4 * 16 + l16] = f2bf(o);
        }
}

// ---------- launch ----------
extern "C" void kernel_launch(void* const* d_in, const int* in_sizes, int n_in,
                              void* d_out, int out_size, void* d_ws, size_t ws_size,
                              hipStream_t stream) {
    const float* queries = (const float*)d_in[0];
    const float* keys    = (const float*)d_in[1];
    const float* values  = (const float*)d_in[2];
    const float* boxes   = (const float*)d_in[3];
    const float* bq = (const float*)d_in[5];
    const float* bk = (const float*)d_in[7];
    const float* bv = (const float*)d_in[9];
    const float* bo = (const float*)d_in[11];
    const float* Wg = (const float*)d_in[12];
    const float* bg = (const float*)d_in[13];

    char* ws = (char*)d_ws;
    short* qbf = (short*)(ws + 0);
    short* kbf = (short*)(ws + 8388608);
    short* vbf = (short*)(ws + 16777216);
    short* wqb = (short*)(ws + 25165824);
    short* wkb = (short*)(ws + 27262976);
    short* wvb = (short*)(ws + 29360128);
    short* wob = (short*)(ws + 31457280);
    short* Qh  = (short*)(ws + 33554432);
    short* Kh  = (short*)(ws + 41943040);
    short* Vt  = (short*)(ws + 50331648);   // [b][1024 out][512 tok]
    short* Hd  = (short*)(ws + 58720256);   // hidden [4096][1024]
    __half* GL = (__half*)(ws + 67108864);  // [b][h][512][512] f16, 67 MB

    // K0: converts
    convert_f32_bf16<<<4096, 256, 0, stream>>>(queries, qbf, 1048576);
    convert_f32_bf16<<<4096, 256, 0, stream>>>(keys,    kbf, 1048576);
    convert_f32_bf16<<<4096, 256, 0, stream>>>(values,  vbf, 1048576);
    convert_f32_bf16<<<1024, 256, 0, stream>>>((const float*)d_in[4],  wqb, 262144);
    convert_f32_bf16<<<1024, 256, 0, stream>>>((const float*)d_in[6],  wkb, 262144);
    convert_f32_bf16<<<1024, 256, 0, stream>>>((const float*)d_in[8],  wvb, 262144);
    convert_f32_bf16<<<1024, 256, 0, stream>>>((const float*)d_in[10], wob, 262144);

    // K1: geometry bias
    geom_kernel<<<dim3(2, 512, 8), 256, 0, stream>>>(boxes, Wg, bg, GL);

    // K2: projections.  Q/K: C[tok][out] = X·W^T.   V: C[out][tok] = Wv·X^T (writes Vt directly).
    gemm_bf16<false, false><<<dim3(8, 32, 1), 256, 0, stream>>>(qbf, wqb, 0, bq, Qh, 0, 1024, 1024);
    gemm_bf16<false, false><<<dim3(8, 32, 1), 256, 0, stream>>>(kbf, wkb, 0, bk, Kh, 0, 1024, 1024);
    gemm_bf16<false, true ><<<dim3(4, 8, 8),  256, 0, stream>>>(wvb, vbf, (long)512 * 1024, bv,
                                                                Vt, (long)1024 * 512, 1024, 512);

    // K3: attention
    flash_attn<<<dim3(8, 16, 8), 256, 0, stream>>>(Qh, Kh, Vt, GL, Hd);

    // K4: output projection -> f32 out
    gemm_bf16<true, false><<<dim3(8, 32, 1), 256, 0, stream>>>(Hd, wob, 0, bo, d_out, 0, 1024, 1024);
}

// Round 2
// 433.423 us; speedup vs baseline: 1.2367x; 1.2367x over previous
//
#include <hip/hip_runtime.h>
#include <hip/hip_bf16.h>
#include <hip/hip_fp16.h>

// ---------- common types ----------
typedef __attribute__((ext_vector_type(8))) short bf16x8;      // 8 bf16 = 4 VGPR (MFMA A/B frag)
typedef __attribute__((ext_vector_type(8))) _Float16 f16x8;    // 8 f16  = 4 VGPR (MFMA A/B frag)
typedef __attribute__((ext_vector_type(4))) float f32x4;       // MFMA C/D frag

__device__ __forceinline__ short f2bf(float x) {
    unsigned u = __builtin_bit_cast(unsigned, x);
    u += 0x7fffu + ((u >> 16) & 1u);          // RNE
    return (short)(u >> 16);
}

// ---------- K0: f32 -> bf16 convert (vectorized x4) ----------
__global__ void convert_f32_bf16(const float* __restrict__ src, short* __restrict__ dst, int n4) {
    int i = blockIdx.x * blockDim.x + threadIdx.x;
    if (i < n4) {
        float4 v = reinterpret_cast<const float4*>(src)[i];
        short4 o;
        o.x = f2bf(v.x); o.y = f2bf(v.y); o.z = f2bf(v.z); o.w = f2bf(v.w);
        reinterpret_cast<short4*>(dst)[i] = o;
    }
}

// ---------- K0b: f32 -> f16 convert (small, for Wg) ----------
__global__ void convert_f32_f16(const float* __restrict__ src, _Float16* __restrict__ dst, int n) {
    int i = blockIdx.x * blockDim.x + threadIdx.x;
    if (i < n) dst[i] = (_Float16)src[i];
}

// ---------- K1: geometry bias via MFMA projection ----------
// block = 256 thr = 4 waves; covers one n, m-tile of 64, all 16 heads.
// Each wave: 16 pairs. Lane l -> pair p=l>>2, component c=l&3 computes 8 sin + 8 cos
// f16 features to LDS; then 2x mfma_f32_16x16x32_f16 projects to 16 heads
// (A = features [16 pair x 64], B = Wg-f16 [16 head x 64]); epilogue log(max(z,1e-6));
// LDS transpose -> block-cooperative full-line stores (each wave: 4 x 128B lines).
__global__ void geom_kernel2(const float* __restrict__ boxes, const _Float16* __restrict__ Wgh,
                             const float* __restrict__ bg, __half* __restrict__ GL) {
    const int tid = threadIdx.x;
    const int wave = tid >> 6, lane = tid & 63, quad = lane >> 4, l16 = lane & 15;
    const int m0 = blockIdx.x * 64;
    const int n = blockIdx.y;
    const int b = blockIdx.z;

    __shared__ __align__(16) _Float16 feat[4][16][72];   // +8 pad: A-frag b128 reads land 2-way (free)
    __shared__ __align__(16) _Float16 lgbuf[16][68];     // [head][m-local], +4 pad

    // ---- features ----
    const int p = lane >> 2;          // pair within wave (0..15)
    const int c = lane & 3;           // pos component
    const int m = m0 + wave * 16 + p;

    float4 bn = reinterpret_cast<const float4*>(boxes)[b * 512 + n];   // uniform -> scalar
    float4 bm = reinterpret_cast<const float4*>(boxes)[b * 512 + m];
    float cxn = (bn.x + bn.z) * 0.5f, cyn = (bn.y + bn.w) * 0.5f;
    float wn = bn.z - bn.x + 1.0f, hn = bn.w - bn.y + 1.0f;
    float cxm = (bm.x + bm.z) * 0.5f, cym = (bm.y + bm.w) * 0.5f;
    float wm = bm.z - bm.x + 1.0f, hm = bm.w - bm.y + 1.0f;

    float r;
    if (c == 0)      r = fmaxf(fabsf((cxn - cxm) / wn), 1e-3f);
    else if (c == 1) r = fmaxf(fabsf((cyn - cym) / hn), 1e-3f);
    else if (c == 2) r = wn / wm;
    else             r = hn / hm;
    float pos = __logf(r) * 100.0f;

    const float dm[8] = {1.0f, 0.42169651f, 0.17782794f, 0.07498942f,
                         0.03162278f, 0.01333521f, 0.00562341f, 0.00237137f};
    f16x8 sv8, cv8;
    #pragma unroll
    for (int f = 0; f < 8; ++f) {
        float th = pos * dm[f];
        sv8[f] = (_Float16)__sinf(th);
        cv8[f] = (_Float16)__cosf(th);
    }
    *(f16x8*)&feat[wave][p][c * 8]      = sv8;   // k-order matches Wg: [c][f] sin, then cos
    *(f16x8*)&feat[wave][p][32 + c * 8] = cv8;

    __syncthreads();

    // ---- MFMA projection: C[pair][head] ----
    f16x8 a0 = *(const f16x8*)&feat[wave][l16][quad * 8];
    f16x8 a1 = *(const f16x8*)&feat[wave][l16][32 + quad * 8];
    f16x8 b0 = *(const f16x8*)(Wgh + l16 * 64 + quad * 8);
    f16x8 b1 = *(const f16x8*)(Wgh + l16 * 64 + 32 + quad * 8);
    f32x4 acc = (f32x4){0.f, 0.f, 0.f, 0.f};
    acc = __builtin_amdgcn_mfma_f32_16x16x32_f16(a0, b0, acc, 0, 0, 0);
    acc = __builtin_amdgcn_mfma_f32_16x16x32_f16(a1, b1, acc, 0, 0, 0);

    // ---- epilogue: relu+clip+log, transpose via LDS ----
    float bgv = bg[l16];              // col = head = l16
    #pragma unroll
    for (int rr = 0; rr < 4; ++rr) {
        float g = fmaxf(acc[rr] + bgv, 1e-6f);        // relu then clip == max(z,1e-6)
        lgbuf[l16][wave * 16 + quad * 4 + rr] = (_Float16)__logf(g);
    }
    __syncthreads();

    // ---- block-cooperative stores: full aligned 128B lines per wave ----
    const int h = tid >> 4, seg = tid & 15;
    ushort4 v = *(const ushort4*)&lgbuf[h][seg * 4];
    *(ushort4*)&GL[((long)((b * 16 + h) * 512 + n)) * 512 + m0 + seg * 4] = v;
}

// ---------- K2/K4: GEMM  C[m][n] = sum_k A[m][k] * B[n][k]  (+bias) ----------
// A: MxK row-major bf16, B: NxK row-major bf16. 128x128 workgroup tile,
// 4 waves in 2x2, each wave 64x64 (4x4 C-frags), direct-from-global fragments.
template<bool OUT_F32, bool BIAS_M>
__global__ void gemm_bf16(const short* __restrict__ A, const short* __restrict__ B, long sB,
                          const float* __restrict__ bias, void* __restrict__ Cv, long sC,
                          int K, int ldc) {
    const int tid = threadIdx.x;
    const int wave = tid >> 6, lane = tid & 63, quad = lane >> 4, l16 = lane & 15;
    const int m0 = blockIdx.y * 128 + (wave >> 1) * 64;
    const int n0 = blockIdx.x * 128 + (wave & 1) * 64;
    const short* Bp = B + (long)blockIdx.z * sB;

    f32x4 acc[4][4];
    #pragma unroll
    for (int mg = 0; mg < 4; ++mg)
        #pragma unroll
        for (int ng = 0; ng < 4; ++ng)
            acc[mg][ng] = (f32x4){0.f, 0.f, 0.f, 0.f};

    const short* a_base = A  + (long)(m0 + l16) * K + quad * 8;
    const short* b_base = Bp + (long)(n0 + l16) * K + quad * 8;

    for (int k0 = 0; k0 < K; k0 += 32) {
        bf16x8 a[4], bb[4];
        #pragma unroll
        for (int g = 0; g < 4; ++g) {
            a[g]  = *(const bf16x8*)(a_base + (long)g * 16 * K + k0);
            bb[g] = *(const bf16x8*)(b_base + (long)g * 16 * K + k0);
        }
        #pragma unroll
        for (int mg = 0; mg < 4; ++mg)
            #pragma unroll
            for (int ng = 0; ng < 4; ++ng)
                acc[mg][ng] = __builtin_amdgcn_mfma_f32_16x16x32_bf16(a[mg], bb[ng], acc[mg][ng], 0, 0, 0);
    }

    #pragma unroll
    for (int mg = 0; mg < 4; ++mg)
        #pragma unroll
        for (int ng = 0; ng < 4; ++ng)
            #pragma unroll
            for (int r = 0; r < 4; ++r) {
                int row = m0 + mg * 16 + quad * 4 + r;
                int col = n0 + ng * 16 + l16;
                float v = acc[mg][ng][r] + (BIAS_M ? bias[row] : bias[col]);
                long ci = (long)blockIdx.z * sC + (long)row * ldc + col;
                if constexpr (OUT_F32) ((float*)Cv)[ci] = v;
                else                   ((short*)Cv)[ci] = f2bf(v);
            }
}

// ---------- K3: flash attention with geometric bias ----------
// grid (qt=8, h=16, b=8), 256 threads = 4 waves, each wave 16 q-rows, k-tiles of 64.
__global__ void flash_attn(const short* __restrict__ Q, const short* __restrict__ Kh,
                           const short* __restrict__ Vt, const __half* __restrict__ GL,
                           short* __restrict__ O) {
    const int tid = threadIdx.x;
    const int wave = tid >> 6, lane = tid & 63, quad = lane >> 4, l16 = lane & 15;
    const int qt = blockIdx.x, h = blockIdx.y, b = blockIdx.z;

    __shared__ __align__(16) short Pbuf[4][16][72];   // +8 pad: ds_read_b128 lands 2-way (free)

    const int qrow = qt * 64 + wave * 16;
    const long qoff = ((long)(b * 512 + qrow + l16)) * 1024 + h * 64 + quad * 8;
    bf16x8 aq0 = *(const bf16x8*)(Q + qoff);
    bf16x8 aq1 = *(const bf16x8*)(Q + qoff + 32);

    f32x4 oacc[4];
    float mi[4], li[4];
    #pragma unroll
    for (int r = 0; r < 4; ++r) {
        oacc[r] = (f32x4){0.f, 0.f, 0.f, 0.f};
        mi[r] = -1e30f; li[r] = 0.f;
    }

    for (int kt = 0; kt < 8; ++kt) {
        float lg[4][4];
        #pragma unroll
        for (int nk = 0; nk < 4; ++nk) {
            const long koff = ((long)(b * 512 + kt * 64 + nk * 16 + l16)) * 1024 + h * 64 + quad * 8;
            bf16x8 bk0 = *(const bf16x8*)(Kh + koff);
            bf16x8 bk1 = *(const bf16x8*)(Kh + koff + 32);
            f32x4 s = (f32x4){0.f, 0.f, 0.f, 0.f};
            s = __builtin_amdgcn_mfma_f32_16x16x32_bf16(aq0, bk0, s, 0, 0, 0);
            s = __builtin_amdgcn_mfma_f32_16x16x32_bf16(aq1, bk1, s, 0, 0, 0);
            #pragma unroll
            for (int r = 0; r < 4; ++r) {
                float gl = __half2float(GL[((long)((b * 16 + h) * 512 + qrow + quad * 4 + r)) * 512
                                           + kt * 64 + nk * 16 + l16]);
                lg[nk][r] = s[r] * 0.125f + gl;
            }
        }
        float mnew[4], alpha[4], rs[4];
        #pragma unroll
        for (int r = 0; r < 4; ++r) {
            float mx = fmaxf(fmaxf(lg[0][r], lg[1][r]), fmaxf(lg[2][r], lg[3][r]));
            mx = fmaxf(mx, __shfl_xor(mx, 1));
            mx = fmaxf(mx, __shfl_xor(mx, 2));
            mx = fmaxf(mx, __shfl_xor(mx, 4));
            mx = fmaxf(mx, __shfl_xor(mx, 8));
            mnew[r] = fmaxf(mi[r], mx);
            alpha[r] = __expf(mi[r] - mnew[r]);
            mi[r] = mnew[r];
            rs[r] = 0.f;
        }
        #pragma unroll
        for (int nk = 0; nk < 4; ++nk)
            #pragma unroll
            for (int r = 0; r < 4; ++r) { float p = __expf(lg[nk][r] - mnew[r]); lg[nk][r] = p; rs[r] += p; }
        #pragma unroll
        for (int r = 0; r < 4; ++r) {
            float s4 = rs[r];
            s4 += __shfl_xor(s4, 1); s4 += __shfl_xor(s4, 2);
            s4 += __shfl_xor(s4, 4); s4 += __shfl_xor(s4, 8);
            li[r] = li[r] * alpha[r] + s4;
        }
        #pragma unroll
        for (int n4 = 0; n4 < 4; ++n4)
            #pragma unroll
            for (int r = 0; r < 4; ++r) oacc[n4][r] *= alpha[r];

        __syncthreads();   // protect Pbuf WAR across iterations
        #pragma unroll
        for (int nk = 0; nk < 4; ++nk)
            #pragma unroll
            for (int r = 0; r < 4; ++r)
                Pbuf[wave][quad * 4 + r][nk * 16 + l16] = f2bf(lg[nk][r]);
        __syncthreads();

        // P in A-frag layout from LDS; V from global (Vt is [b][1024][512], K-contiguous)
        bf16x8 ap0 = *(const bf16x8*)&Pbuf[wave][l16][quad * 8];
        bf16x8 ap1 = *(const bf16x8*)&Pbuf[wave][l16][32 + quad * 8];
        #pragma unroll
        for (int n4 = 0; n4 < 4; ++n4) {
            const long voff = ((long)(b * 1024 + h * 64 + n4 * 16 + l16)) * 512 + kt * 64 + quad * 8;
            bf16x8 bv0 = *(const bf16x8*)(Vt + voff);
            bf16x8 bv1 = *(const bf16x8*)(Vt + voff + 32);
            oacc[n4] = __builtin_amdgcn_mfma_f32_16x16x32_bf16(ap0, bv0, oacc[n4], 0, 0, 0);
            oacc[n4] = __builtin_amdgcn_mfma_f32_16x16x32_bf16(ap1, bv1, oacc[n4], 0, 0, 0);
        }
    }

    #pragma unroll
    for (int n4 = 0; n4 < 4; ++n4)
        #pragma unroll
        for (int r = 0; r < 4; ++r) {
            float o = oacc[n4][r] / li[r];
            O[((long)(b * 512 + qrow + quad * 4 + r)) * 1024 + h * 64 + n4 * 16 + l16] = f2bf(o);
        }
}

// ---------- launch ----------
extern "C" void kernel_launch(void* const* d_in, const int* in_sizes, int n_in,
                              void* d_out, int out_size, void* d_ws, size_t ws_size,
                              hipStream_t stream) {
    const float* queries = (const float*)d_in[0];
    const float* keys    = (const float*)d_in[1];
    const float* values  = (const float*)d_in[2];
    const float* boxes   = (const float*)d_in[3];
    const float* bq = (const float*)d_in[5];
    const float* bk = (const float*)d_in[7];
    const float* bv = (const float*)d_in[9];
    const float* bo = (const float*)d_in[11];
    const float* Wg = (const float*)d_in[12];
    const float* bg = (const float*)d_in[13];

    char* ws = (char*)d_ws;
    short* qbf = (short*)(ws + 0);
    short* kbf = (short*)(ws + 8388608);
    short* vbf = (short*)(ws + 16777216);
    short* wqb = (short*)(ws + 25165824);
    short* wkb = (short*)(ws + 27262976);
    short* wvb = (short*)(ws + 29360128);
    short* wob = (short*)(ws + 31457280);
    short* Qh  = (short*)(ws + 33554432);
    short* Kh  = (short*)(ws + 41943040);
    short* Vt  = (short*)(ws + 50331648);   // [b][1024 out][512 tok]
    short* Hd  = (short*)(ws + 58720256);   // hidden [4096][1024]
    __half* GL = (__half*)(ws + 67108864);  // [b][h][512][512] f16, 67 MB
    // Wgh overlaps Qh's region: Wgh is dead before the Q-projection GEMM writes Qh.
    _Float16* Wgh = (_Float16*)(ws + 33554432);

    // K0: converts
    convert_f32_bf16<<<4096, 256, 0, stream>>>(queries, qbf, 1048576);
    convert_f32_bf16<<<4096, 256, 0, stream>>>(keys,    kbf, 1048576);
    convert_f32_bf16<<<4096, 256, 0, stream>>>(values,  vbf, 1048576);
    convert_f32_bf16<<<1024, 256, 0, stream>>>((const float*)d_in[4],  wqb, 262144);
    convert_f32_bf16<<<1024, 256, 0, stream>>>((const float*)d_in[6],  wkb, 262144);
    convert_f32_bf16<<<1024, 256, 0, stream>>>((const float*)d_in[8],  wvb, 262144);
    convert_f32_bf16<<<1024, 256, 0, stream>>>((const float*)d_in[10], wob, 262144);
    convert_f32_f16<<<4, 256, 0, stream>>>(Wg, Wgh, 1024);

    // K1: geometry bias (MFMA projection)
    geom_kernel2<<<dim3(8, 512, 8), 256, 0, stream>>>(boxes, Wgh, bg, GL);

    // K2: projections.  Q/K: C[tok][out] = X·W^T.   V: C[out][tok] = Wv·X^T (writes Vt directly).
    gemm_bf16<false, false><<<dim3(8, 32, 1), 256, 0, stream>>>(qbf, wqb, 0, bq, Qh, 0, 1024, 1024);
    gemm_bf16<false, false><<<dim3(8, 32, 1), 256, 0, stream>>>(kbf, wkb, 0, bk, Kh, 0, 1024, 1024);
    gemm_bf16<false, true ><<<dim3(4, 8, 8),  256, 0, stream>>>(wvb, vbf, (long)512 * 1024, bv,
                                                                Vt, (long)1024 * 512, 1024, 512);

    // K3: attention
    flash_attn<<<dim3(8, 16, 8), 256, 0, stream>>>(Qh, Kh, Vt, GL, Hd);

    // K4: output projection -> f32 out
    gemm_bf16<true, false><<<dim3(8, 32, 1), 256, 0, stream>>>(Hd, wob, 0, bo, d_out, 0, 1024, 1024);
}

// Round 5
// 335.594 us; speedup vs baseline: 1.5972x; 1.2915x over previous
//
#include <hip/hip_runtime.h>
#include <hip/hip_bf16.h>
#include <hip/hip_fp16.h>

// ---------- common types ----------
typedef __attribute__((ext_vector_type(8))) short bf16x8;      // 8 bf16 = 4 VGPR (MFMA A/B frag)
typedef __attribute__((ext_vector_type(8))) _Float16 f16x8;    // 8 f16  = 4 VGPR (MFMA A/B frag)
typedef __attribute__((ext_vector_type(4))) float f32x4;       // MFMA C/D frag
typedef __attribute__((ext_vector_type(8))) short short8;      // 16B staging chunk

__device__ __forceinline__ short f2bf(float x) {
    unsigned u = __builtin_bit_cast(unsigned, x);
    u += 0x7fffu + ((u >> 16) & 1u);          // RNE
    return (short)(u >> 16);
}

// async global->LDS, 16B per lane. lds dst must be wave-uniform base; HW scatters lane*16.
__device__ __forceinline__ void load_lds16(const void* g, void* l) {
    __builtin_amdgcn_global_load_lds((const __attribute__((address_space(1))) unsigned int*)g,
                                     (__attribute__((address_space(3))) unsigned int*)l, 16, 0, 0);
}

// ---------- K0: fused converts ----------
// q/k/v: 8*512*1024 floats = 1048576 float4 each  ->  grid (4096, 3)
__global__ void convert_qkv(const float* __restrict__ q, const float* __restrict__ k,
                            const float* __restrict__ v, short* __restrict__ qo,
                            short* __restrict__ ko, short* __restrict__ vo) {
    int i = blockIdx.x * 256 + threadIdx.x;
    const float* s = blockIdx.y == 0 ? q : blockIdx.y == 1 ? k : v;
    short* d = blockIdx.y == 0 ? qo : blockIdx.y == 1 ? ko : vo;
    float4 val = reinterpret_cast<const float4*>(s)[i];
    short4 o; o.x = f2bf(val.x); o.y = f2bf(val.y); o.z = f2bf(val.z); o.w = f2bf(val.w);
    reinterpret_cast<short4*>(d)[i] = o;
}

// weights: 1024*1024 floats = 262144 float4 each  ->  grid (1024, 4)
__global__ void convert_w4(const float* __restrict__ w0, const float* __restrict__ w1,
                           const float* __restrict__ w2, const float* __restrict__ w3,
                           short* __restrict__ o0, short* __restrict__ o1,
                           short* __restrict__ o2, short* __restrict__ o3) {
    int i = blockIdx.x * 256 + threadIdx.x;
    const float* s = blockIdx.y == 0 ? w0 : blockIdx.y == 1 ? w1 : blockIdx.y == 2 ? w2 : w3;
    short* d = blockIdx.y == 0 ? o0 : blockIdx.y == 1 ? o1 : blockIdx.y == 2 ? o2 : o3;
    float4 val = reinterpret_cast<const float4*>(s)[i];
    short4 o; o.x = f2bf(val.x); o.y = f2bf(val.y); o.z = f2bf(val.z); o.w = f2bf(val.w);
    reinterpret_cast<short4*>(d)[i] = o;
}

__global__ void convert_f32_f16(const float* __restrict__ src, _Float16* __restrict__ dst, int n) {
    int i = blockIdx.x * blockDim.x + threadIdx.x;
    if (i < n) dst[i] = (_Float16)src[i];
}

// ---------- K1: geometry bias via MFMA projection; stores g (NOT log g), f16 ----------
__global__ void geom_kernel2(const float* __restrict__ boxes, const _Float16* __restrict__ Wgh,
                             const float* __restrict__ bg, __half* __restrict__ G) {
    const int tid = threadIdx.x;
    const int wave = tid >> 6, lane = tid & 63, quad = lane >> 4, l16 = lane & 15;
    const int m0 = blockIdx.x * 64;
    const int n = blockIdx.y;
    const int b = blockIdx.z;

    __shared__ __align__(16) _Float16 feat[4][16][72];
    __shared__ __align__(16) _Float16 gbuf[16][68];

    const int p = lane >> 2, c = lane & 3;
    const int m = m0 + wave * 16 + p;

    float4 bn = reinterpret_cast<const float4*>(boxes)[b * 512 + n];
    float4 bm = reinterpret_cast<const float4*>(boxes)[b * 512 + m];
    float cxn = (bn.x + bn.z) * 0.5f, cyn = (bn.y + bn.w) * 0.5f;
    float wn = bn.z - bn.x + 1.0f, hn = bn.w - bn.y + 1.0f;
    float cxm = (bm.x + bm.z) * 0.5f, cym = (bm.y + bm.w) * 0.5f;
    float wm = bm.z - bm.x + 1.0f, hm = bm.w - bm.y + 1.0f;

    float r;
    if (c == 0)      r = fmaxf(fabsf((cxn - cxm) / wn), 1e-3f);
    else if (c == 1) r = fmaxf(fabsf((cyn - cym) / hn), 1e-3f);
    else if (c == 2) r = wn / wm;
    else             r = hn / hm;
    float pos = __logf(r) * 100.0f;

    const float dm[8] = {1.0f, 0.42169651f, 0.17782794f, 0.07498942f,
                         0.03162278f, 0.01333521f, 0.00562341f, 0.00237137f};
    f16x8 sv8, cv8;
    #pragma unroll
    for (int f = 0; f < 8; ++f) {
        float th = pos * dm[f];
        sv8[f] = (_Float16)__sinf(th);
        cv8[f] = (_Float16)__cosf(th);
    }
    *(f16x8*)&feat[wave][p][c * 8]      = sv8;
    *(f16x8*)&feat[wave][p][32 + c * 8] = cv8;

    __syncthreads();

    f16x8 a0 = *(const f16x8*)&feat[wave][l16][quad * 8];
    f16x8 a1 = *(const f16x8*)&feat[wave][l16][32 + quad * 8];
    f16x8 b0 = *(const f16x8*)(Wgh + l16 * 64 + quad * 8);
    f16x8 b1 = *(const f16x8*)(Wgh + l16 * 64 + 32 + quad * 8);
    f32x4 acc = (f32x4){0.f, 0.f, 0.f, 0.f};
    acc = __builtin_amdgcn_mfma_f32_16x16x32_f16(a0, b0, acc, 0, 0, 0);
    acc = __builtin_amdgcn_mfma_f32_16x16x32_f16(a1, b1, acc, 0, 0, 0);

    float bgv = bg[l16];
    #pragma unroll
    for (int rr = 0; rr < 4; ++rr) {
        float g = fmaxf(acc[rr] + bgv, 1e-6f);        // relu + clip; store g itself
        gbuf[l16][wave * 16 + quad * 4 + rr] = (_Float16)g;
    }
    __syncthreads();

    const int h = tid >> 4, seg = tid & 15;
    ushort4 v = *(const ushort4*)&gbuf[h][seg * 4];
    *(ushort4*)&G[((long)((b * 16 + h) * 512 + n)) * 512 + m0 + seg * 4] = v;
}

// ---------- K2/K4: LDS-staged GEMM (m97 structure) ----------
// C[m][n] = sum_k A[m][k]*B[n][k] + bias. 128x128 tile, BK=32, global_load_lds w=16.
template<bool OUT_F32, bool BIAS_M>
__global__ void gemm_lds(const short* __restrict__ A, const short* __restrict__ B, long sB,
                         const float* __restrict__ bias, void* __restrict__ Cv, long sC,
                         int K, int ldc) {
    __shared__ __align__(16) short As[4096];   // [128][32]
    __shared__ __align__(16) short Bs[4096];
    const int tid = threadIdx.x;
    const int wave = tid >> 6, lane = tid & 63, quad = lane >> 4, l16 = lane & 15;
    const int m0 = blockIdx.y * 128, n0 = blockIdx.x * 128;
    const short* Ap = A + (long)m0 * K;
    const short* Bp = B + (long)blockIdx.z * sB + (long)n0 * K;

    f32x4 acc[4][4];
    #pragma unroll
    for (int mg = 0; mg < 4; ++mg)
        #pragma unroll
        for (int ng = 0; ng < 4; ++ng) acc[mg][ng] = (f32x4){0.f, 0.f, 0.f, 0.f};

    // staging map: flat element (j*256+tid)*8 -> row (j*256+tid)/4, kcol (tid&3)*8
    const int r0 = tid >> 2, kk = (tid & 3) * 8;
    const short* ga0 = Ap + (long)r0 * K + kk;
    const short* ga1 = Ap + (long)(64 + r0) * K + kk;
    const short* gb0 = Bp + (long)r0 * K + kk;
    const short* gb1 = Bp + (long)(64 + r0) * K + kk;
    short* la0 = As + wave * 512;          // wave-uniform LDS bases
    short* la1 = As + 2048 + wave * 512;
    short* lb0 = Bs + wave * 512;
    short* lb1 = Bs + 2048 + wave * 512;

    const int mw = (wave >> 1) * 64, nw = (wave & 1) * 64;

    for (int k0 = 0; k0 < K; k0 += 32) {
        load_lds16(ga0 + k0, la0);
        load_lds16(ga1 + k0, la1);
        load_lds16(gb0 + k0, lb0);
        load_lds16(gb1 + k0, lb1);
        __syncthreads();                   // vmcnt(0) drain: tile visible
        bf16x8 a[4], bb[4];
        #pragma unroll
        for (int g = 0; g < 4; ++g) {
            a[g]  = *(const bf16x8*)&As[(mw + g * 16 + l16) * 32 + quad * 8];
            bb[g] = *(const bf16x8*)&Bs[(nw + g * 16 + l16) * 32 + quad * 8];
        }
        #pragma unroll
        for (int mg = 0; mg < 4; ++mg)
            #pragma unroll
            for (int ng = 0; ng < 4; ++ng)
                acc[mg][ng] = __builtin_amdgcn_mfma_f32_16x16x32_bf16(a[mg], bb[ng], acc[mg][ng], 0, 0, 0);
        __syncthreads();                   // WAR before next stage
    }

    #pragma unroll
    for (int mg = 0; mg < 4; ++mg)
        #pragma unroll
        for (int ng = 0; ng < 4; ++ng)
            #pragma unroll
            for (int r = 0; r < 4; ++r) {
                int row = m0 + mw + mg * 16 + quad * 4 + r;   // FIX: + mw
                int col = n0 + nw + ng * 16 + l16;            // FIX: + nw
                float v = acc[mg][ng][r] + (BIAS_M ? bias[row] : bias[col]);
                long ci = (long)blockIdx.z * sC + (long)row * ldc + col;
                if constexpr (OUT_F32) ((float*)Cv)[ci] = v;
                else                   ((short*)Cv)[ci] = f2bf(v);
            }
}

// ---------- K3: flash attention, max-free softmax (p = g * exp(s/8)) ----------
// grid (qt=8, h=16, b=8), 256 thr = 4 waves, each wave 16 q-rows.
__global__ void flash_attn2(const short* __restrict__ Q, const short* __restrict__ Kh,
                            const short* __restrict__ Vt, const __half* __restrict__ G,
                            short* __restrict__ O) {
    const int tid = threadIdx.x;
    const int wave = tid >> 6, lane = tid & 63, quad = lane >> 4, l16 = lane & 15;
    const int qt = blockIdx.x, h = blockIdx.y, b = blockIdx.z;

    __shared__ __align__(16) short Pbuf[4][16][72];
    __shared__ __align__(16) __half Gs[64][72];    // 64q x 64k tile, stride 72 (16B-aligned rows)

    const int qrow = qt * 64 + wave * 16;
    const long qoff = ((long)(b * 512 + qrow + l16)) * 1024 + h * 64 + quad * 8;
    bf16x8 aq0 = *(const bf16x8*)(Q + qoff);
    bf16x8 aq1 = *(const bf16x8*)(Q + qoff + 32);

    const __half* gbase = G + ((long)((b * 16 + h) * 512 + qt * 64)) * 512;

    f32x4 oacc[4];
    float rs[4];
    #pragma unroll
    for (int r = 0; r < 4; ++r) { oacc[r] = (f32x4){0.f, 0.f, 0.f, 0.f}; rs[r] = 0.f; }

    for (int kt = 0; kt < 8; ++kt) {
        __syncthreads();   // WAR: prev iter's Gs reads done
        // stage Gs: 64 rows x 64 cols f16; 512 x 16B chunks; 2 per thread
        #pragma unroll
        for (int j = 0; j < 2; ++j) {
            int c = j * 256 + tid;
            int row = c >> 3, col = (c & 7) * 8;
            short8 v = *(const short8*)(gbase + (long)row * 512 + kt * 64 + col);
            *(short8*)&Gs[row][col] = v;
        }
        // QK^T (independent of Gs -> overlaps staging)
        float s[4][4];
        #pragma unroll
        for (int nk = 0; nk < 4; ++nk) {
            const long koff = ((long)(b * 512 + kt * 64 + nk * 16 + l16)) * 1024 + h * 64 + quad * 8;
            bf16x8 bk0 = *(const bf16x8*)(Kh + koff);
            bf16x8 bk1 = *(const bf16x8*)(Kh + koff + 32);
            f32x4 sc = (f32x4){0.f, 0.f, 0.f, 0.f};
            sc = __builtin_amdgcn_mfma_f32_16x16x32_bf16(aq0, bk0, sc, 0, 0, 0);
            sc = __builtin_amdgcn_mfma_f32_16x16x32_bf16(aq1, bk1, sc, 0, 0, 0);
            #pragma unroll
            for (int r = 0; r < 4; ++r) s[nk][r] = sc[r];
        }
        __syncthreads();   // Gs visible
        // p = g * exp(s/8); accumulate per-lane row sums; write Pbuf
        #pragma unroll
        for (int nk = 0; nk < 4; ++nk)
            #pragma unroll
            for (int r = 0; r < 4; ++r) {
                float g = __half2float(Gs[wave * 16 + quad * 4 + r][nk * 16 + l16]);
                float p = g * __expf(s[nk][r] * 0.125f);
                rs[r] += p;
                Pbuf[wave][quad * 4 + r][nk * 16 + l16] = f2bf(p);
            }
        // Pbuf is per-wave private: in-order LDS within the wave suffices
        bf16x8 ap0 = *(const bf16x8*)&Pbuf[wave][l16][quad * 8];
        bf16x8 ap1 = *(const bf16x8*)&Pbuf[wave][l16][32 + quad * 8];
        #pragma unroll
        for (int n4 = 0; n4 < 4; ++n4) {
            const long voff = ((long)(b * 1024 + h * 64 + n4 * 16 + l16)) * 512 + kt * 64 + quad * 8;
            bf16x8 bv0 = *(const bf16x8*)(Vt + voff);
            bf16x8 bv1 = *(const bf16x8*)(Vt + voff + 32);
            oacc[n4] = __builtin_amdgcn_mfma_f32_16x16x32_bf16(ap0, bv0, oacc[n4], 0, 0, 0);
            oacc[n4] = __builtin_amdgcn_mfma_f32_16x16x32_bf16(ap1, bv1, oacc[n4], 0, 0, 0);
        }
    }

    // one final reduction over the 16 column-lanes
    float li[4];
    #pragma unroll
    for (int r = 0; r < 4; ++r) {
        float s4 = rs[r];
        s4 += __shfl_xor(s4, 1); s4 += __shfl_xor(s4, 2);
        s4 += __shfl_xor(s4, 4); s4 += __shfl_xor(s4, 8);
        li[r] = s4;
    }
    #pragma unroll
    for (int n4 = 0; n4 < 4; ++n4)
        #pragma unroll
        for (int r = 0; r < 4; ++r) {
            float o = oacc[n4][r] / li[r];
            O[((long)(b * 512 + qrow + quad * 4 + r)) * 1024 + h * 64 + n4 * 16 + l16] = f2bf(o);
        }
}

// ---------- launch ----------
extern "C" void kernel_launch(void* const* d_in, const int* in_sizes, int n_in,
                              void* d_out, int out_size, void* d_ws, size_t ws_size,
                              hipStream_t stream) {
    const float* queries = (const float*)d_in[0];
    const float* keys    = (const float*)d_in[1];
    const float* values  = (const float*)d_in[2];
    const float* boxes   = (const float*)d_in[3];
    const float* bq = (const float*)d_in[5];
    const float* bk = (const float*)d_in[7];
    const float* bv = (const float*)d_in[9];
    const float* bo = (const float*)d_in[11];
    const float* Wg = (const float*)d_in[12];
    const float* bg = (const float*)d_in[13];

    char* ws = (char*)d_ws;
    short* qbf = (short*)(ws + 0);
    short* kbf = (short*)(ws + 8388608);
    short* vbf = (short*)(ws + 16777216);
    short* wqb = (short*)(ws + 25165824);
    short* wkb = (short*)(ws + 27262976);
    short* wvb = (short*)(ws + 29360128);
    short* wob = (short*)(ws + 31457280);
    short* Qh  = (short*)(ws + 33554432);
    short* Kh  = (short*)(ws + 41943040);
    short* Vt  = (short*)(ws + 50331648);   // [b][1024 out][512 tok]
    short* Hd  = (short*)(ws + 58720256);   // hidden [4096][1024]
    __half* G  = (__half*)(ws + 67108864);  // g [b][h][512][512] f16, 67 MB
    _Float16* Wgh = (_Float16*)(ws + 33554432);  // overlaps Qh (dead before Q-proj)

    convert_qkv<<<dim3(4096, 3), 256, 0, stream>>>(queries, keys, values, qbf, kbf, vbf);
    convert_w4<<<dim3(1024, 4), 256, 0, stream>>>((const float*)d_in[4], (const float*)d_in[6],
                                                  (const float*)d_in[8], (const float*)d_in[10],
                                                  wqb, wkb, wvb, wob);
    convert_f32_f16<<<4, 256, 0, stream>>>(Wg, Wgh, 1024);

    geom_kernel2<<<dim3(8, 512, 8), 256, 0, stream>>>(boxes, Wgh, bg, G);

    gemm_lds<false, false><<<dim3(8, 32, 1), 256, 0, stream>>>(qbf, wqb, 0, bq, Qh, 0, 1024, 1024);
    gemm_lds<false, false><<<dim3(8, 32, 1), 256, 0, stream>>>(kbf, wkb, 0, bk, Kh, 0, 1024, 1024);
    gemm_lds<false, true ><<<dim3(4, 8, 8),  256, 0, stream>>>(wvb, vbf, (long)512 * 1024, bv,
                                                               Vt, (long)1024 * 512, 1024, 512);

    flash_attn2<<<dim3(8, 16, 8), 256, 0, stream>>>(Qh, Kh, Vt, G, Hd);

    gemm_lds<true, false><<<dim3(8, 32, 1), 256, 0, stream>>>(Hd, wob, 0, bo, d_out, 0, 1024, 1024);
}

// Round 6
// 319.067 us; speedup vs baseline: 1.6799x; 1.0518x over previous
//
#include <hip/hip_runtime.h>
#include <hip/hip_bf16.h>
#include <hip/hip_fp16.h>

// ---------- common types ----------
typedef __attribute__((ext_vector_type(8))) short bf16x8;      // 8 bf16 = 4 VGPR (MFMA A/B frag)
typedef __attribute__((ext_vector_type(8))) _Float16 f16x8;    // 8 f16  = 4 VGPR (MFMA A/B frag)
typedef __attribute__((ext_vector_type(4))) float f32x4;       // MFMA C/D frag
typedef __attribute__((ext_vector_type(8))) short short8;      // 16B chunk

__device__ __forceinline__ short f2bf(float x) {
    unsigned u = __builtin_bit_cast(unsigned, x);
    u += 0x7fffu + ((u >> 16) & 1u);          // RNE
    return (short)(u >> 16);
}

// async global->LDS, 16B per lane. lds dst must be wave-uniform base; HW scatters lane*16.
__device__ __forceinline__ void load_lds16(const void* g, void* l) {
    __builtin_amdgcn_global_load_lds((const __attribute__((address_space(1))) unsigned int*)g,
                                     (__attribute__((address_space(3))) unsigned int*)l, 16, 0, 0);
}

// ---------- K0: fused converts ----------
// q/k/v: 1048576 float4 each -> grid (4096, 3)
__global__ void convert_qkv(const float* __restrict__ q, const float* __restrict__ k,
                            const float* __restrict__ v, short* __restrict__ qo,
                            short* __restrict__ ko, short* __restrict__ vo) {
    int i = blockIdx.x * 256 + threadIdx.x;
    const float* s = blockIdx.y == 0 ? q : blockIdx.y == 1 ? k : v;
    short* d = blockIdx.y == 0 ? qo : blockIdx.y == 1 ? ko : vo;
    float4 val = reinterpret_cast<const float4*>(s)[i];
    short4 o; o.x = f2bf(val.x); o.y = f2bf(val.y); o.z = f2bf(val.z); o.w = f2bf(val.w);
    reinterpret_cast<short4*>(d)[i] = o;
}

// weights: 262144 float4 each -> grid (1024, 4)
__global__ void convert_w4(const float* __restrict__ w0, const float* __restrict__ w1,
                           const float* __restrict__ w2, const float* __restrict__ w3,
                           short* __restrict__ o0, short* __restrict__ o1,
                           short* __restrict__ o2, short* __restrict__ o3) {
    int i = blockIdx.x * 256 + threadIdx.x;
    const float* s = blockIdx.y == 0 ? w0 : blockIdx.y == 1 ? w1 : blockIdx.y == 2 ? w2 : w3;
    short* d = blockIdx.y == 0 ? o0 : blockIdx.y == 1 ? o1 : blockIdx.y == 2 ? o2 : o3;
    float4 val = reinterpret_cast<const float4*>(s)[i];
    short4 o; o.x = f2bf(val.x); o.y = f2bf(val.y); o.z = f2bf(val.z); o.w = f2bf(val.w);
    reinterpret_cast<short4*>(d)[i] = o;
}

__global__ void convert_f32_f16(const float* __restrict__ src, _Float16* __restrict__ dst, int n) {
    int i = blockIdx.x * blockDim.x + threadIdx.x;
    if (i < n) dst[i] = (_Float16)src[i];
}

// ---------- K1: geometry bias via MFMA projection; stores g (f16, [b][h][n][m]) ----------
__global__ void geom_kernel2(const float* __restrict__ boxes, const _Float16* __restrict__ Wgh,
                             const float* __restrict__ bg, __half* __restrict__ G) {
    const int tid = threadIdx.x;
    const int wave = tid >> 6, lane = tid & 63, quad = lane >> 4, l16 = lane & 15;
    const int m0 = blockIdx.x * 64;
    const int n = blockIdx.y;
    const int b = blockIdx.z;

    __shared__ __align__(16) _Float16 feat[4][16][72];
    __shared__ __align__(16) _Float16 gbuf[16][68];

    const int p = lane >> 2, c = lane & 3;
    const int m = m0 + wave * 16 + p;

    float4 bn = reinterpret_cast<const float4*>(boxes)[b * 512 + n];
    float4 bm = reinterpret_cast<const float4*>(boxes)[b * 512 + m];
    float cxn = (bn.x + bn.z) * 0.5f, cyn = (bn.y + bn.w) * 0.5f;
    float wn = bn.z - bn.x + 1.0f, hn = bn.w - bn.y + 1.0f;
    float cxm = (bm.x + bm.z) * 0.5f, cym = (bm.y + bm.w) * 0.5f;
    float wm = bm.z - bm.x + 1.0f, hm = bm.w - bm.y + 1.0f;

    float r;
    if (c == 0)      r = fmaxf(fabsf((cxn - cxm) / wn), 1e-3f);
    else if (c == 1) r = fmaxf(fabsf((cyn - cym) / hn), 1e-3f);
    else if (c == 2) r = wn / wm;
    else             r = hn / hm;
    float pos = __logf(r) * 100.0f;

    const float dm[8] = {1.0f, 0.42169651f, 0.17782794f, 0.07498942f,
                         0.03162278f, 0.01333521f, 0.00562341f, 0.00237137f};
    f16x8 sv8, cv8;
    #pragma unroll
    for (int f = 0; f < 8; ++f) {
        float th = pos * dm[f];
        sv8[f] = (_Float16)__sinf(th);
        cv8[f] = (_Float16)__cosf(th);
    }
    *(f16x8*)&feat[wave][p][c * 8]      = sv8;
    *(f16x8*)&feat[wave][p][32 + c * 8] = cv8;

    __syncthreads();

    f16x8 a0 = *(const f16x8*)&feat[wave][l16][quad * 8];
    f16x8 a1 = *(const f16x8*)&feat[wave][l16][32 + quad * 8];
    f16x8 b0 = *(const f16x8*)(Wgh + l16 * 64 + quad * 8);
    f16x8 b1 = *(const f16x8*)(Wgh + l16 * 64 + 32 + quad * 8);
    f32x4 acc = (f32x4){0.f, 0.f, 0.f, 0.f};
    acc = __builtin_amdgcn_mfma_f32_16x16x32_f16(a0, b0, acc, 0, 0, 0);
    acc = __builtin_amdgcn_mfma_f32_16x16x32_f16(a1, b1, acc, 0, 0, 0);

    float bgv = bg[l16];
    #pragma unroll
    for (int rr = 0; rr < 4; ++rr) {
        float g = fmaxf(acc[rr] + bgv, 1e-6f);        // relu + clip; store g itself
        gbuf[l16][wave * 16 + quad * 4 + rr] = (_Float16)g;
    }
    __syncthreads();

    const int h = tid >> 4, seg = tid & 15;
    ushort4 v = *(const ushort4*)&gbuf[h][seg * 4];
    *(ushort4*)&G[((long)((b * 16 + h) * 512 + n)) * 512 + m0 + seg * 4] = v;
}

// ---------- K2/K4: LDS-staged GEMM with z-strided A/B/C (multi-problem batch) ----------
// C[m][n] = sum_k A[m][k]*B[n][k] + bias. 128x128 tile, BK=32, global_load_lds w=16.
// OUT: 0 = bf16, 1 = f32, 2 = f16
template<int OUT, bool BIAS_M>
__global__ __launch_bounds__(256, 2)
void gemm_lds(const short* __restrict__ A, long sAz, const short* __restrict__ B, long sBz,
              const float* __restrict__ bias0, const float* __restrict__ bias1,
              void* __restrict__ Cv, long sCz, int K, int ldc) {
    __shared__ __align__(16) short As[4096];   // [128][32]
    __shared__ __align__(16) short Bs[4096];
    const int tid = threadIdx.x;
    const int wave = tid >> 6, lane = tid & 63, quad = lane >> 4, l16 = lane & 15;
    const int m0 = blockIdx.y * 128, n0 = blockIdx.x * 128;
    const short* Ap = A + (long)blockIdx.z * sAz + (long)m0 * K;
    const short* Bp = B + (long)blockIdx.z * sBz + (long)n0 * K;
    const float* bias = blockIdx.z == 0 ? bias0 : bias1;

    f32x4 acc[4][4];
    #pragma unroll
    for (int mg = 0; mg < 4; ++mg)
        #pragma unroll
        for (int ng = 0; ng < 4; ++ng) acc[mg][ng] = (f32x4){0.f, 0.f, 0.f, 0.f};

    const int r0 = tid >> 2, kk = (tid & 3) * 8;
    const short* ga0 = Ap + (long)r0 * K + kk;
    const short* ga1 = Ap + (long)(64 + r0) * K + kk;
    const short* gb0 = Bp + (long)r0 * K + kk;
    const short* gb1 = Bp + (long)(64 + r0) * K + kk;
    short* la0 = As + wave * 512;          // wave-uniform LDS bases
    short* la1 = As + 2048 + wave * 512;
    short* lb0 = Bs + wave * 512;
    short* lb1 = Bs + 2048 + wave * 512;

    const int mw = (wave >> 1) * 64, nw = (wave & 1) * 64;

    for (int k0 = 0; k0 < K; k0 += 32) {
        load_lds16(ga0 + k0, la0);
        load_lds16(ga1 + k0, la1);
        load_lds16(gb0 + k0, lb0);
        load_lds16(gb1 + k0, lb1);
        __syncthreads();                   // tile visible
        bf16x8 a[4], bb[4];
        #pragma unroll
        for (int g = 0; g < 4; ++g) {
            a[g]  = *(const bf16x8*)&As[(mw + g * 16 + l16) * 32 + quad * 8];
            bb[g] = *(const bf16x8*)&Bs[(nw + g * 16 + l16) * 32 + quad * 8];
        }
        #pragma unroll
        for (int mg = 0; mg < 4; ++mg)
            #pragma unroll
            for (int ng = 0; ng < 4; ++ng)
                acc[mg][ng] = __builtin_amdgcn_mfma_f32_16x16x32_bf16(a[mg], bb[ng], acc[mg][ng], 0, 0, 0);
        __syncthreads();                   // WAR before next stage
    }

    #pragma unroll
    for (int mg = 0; mg < 4; ++mg)
        #pragma unroll
        for (int ng = 0; ng < 4; ++ng)
            #pragma unroll
            for (int r = 0; r < 4; ++r) {
                int row = m0 + mw + mg * 16 + quad * 4 + r;
                int col = n0 + nw + ng * 16 + l16;
                float v = acc[mg][ng][r] + (BIAS_M ? bias[row] : bias[col]);
                long ci = (long)blockIdx.z * sCz + (long)row * ldc + col;
                if constexpr (OUT == 1)      ((float*)Cv)[ci] = v;
                else if constexpr (OUT == 2) ((_Float16*)Cv)[ci] = (_Float16)v;
                else                         ((short*)Cv)[ci] = f2bf(v);
            }
}

// ---------- K3: flash attention, barrier-free, g folded at A-read ----------
// grid (qt=8, h=16, b=8), 256 thr = 4 waves, each wave 16 q-rows.
// P = exp(s/8) stored f16 in wave-private Pbuf; A-frag read multiplied by g
// (contiguous in m for fixed q=l16 -> 2x16B vector loads from row-major G).
__global__ void flash_attn3(const short* __restrict__ Q, const short* __restrict__ Kh,
                            const _Float16* __restrict__ Vt, const __half* __restrict__ G,
                            short* __restrict__ O) {
    const int tid = threadIdx.x;
    const int wave = tid >> 6, lane = tid & 63, quad = lane >> 4, l16 = lane & 15;
    const int qt = blockIdx.x, h = blockIdx.y, b = blockIdx.z;

    __shared__ __align__(16) _Float16 Pbuf[4][16][72];   // per-wave private

    const int qrow = qt * 64 + wave * 16;
    const long qoff = ((long)(b * 512 + qrow + l16)) * 1024 + h * 64 + quad * 8;
    bf16x8 aq0 = *(const bf16x8*)(Q + qoff);
    bf16x8 aq1 = *(const bf16x8*)(Q + qoff + 32);

    // g row for this lane's A-frag q-row (q = l16 within wave tile)
    const _Float16* Gq = (const _Float16*)G +
        ((long)((b * 16 + h) * 512 + qrow + l16)) * 512;

    f32x4 oacc[4];
    #pragma unroll
    for (int r = 0; r < 4; ++r) oacc[r] = (f32x4){0.f, 0.f, 0.f, 0.f};
    float rs = 0.f;   // row-sum for q = l16

    for (int kt = 0; kt < 8; ++kt) {
        // QK^T
        float s[4][4];
        #pragma unroll
        for (int nk = 0; nk < 4; ++nk) {
            const long koff = ((long)(b * 512 + kt * 64 + nk * 16 + l16)) * 1024 + h * 64 + quad * 8;
            bf16x8 bk0 = *(const bf16x8*)(Kh + koff);
            bf16x8 bk1 = *(const bf16x8*)(Kh + koff + 32);
            f32x4 sc = (f32x4){0.f, 0.f, 0.f, 0.f};
            sc = __builtin_amdgcn_mfma_f32_16x16x32_bf16(aq0, bk0, sc, 0, 0, 0);
            sc = __builtin_amdgcn_mfma_f32_16x16x32_bf16(aq1, bk1, sc, 0, 0, 0);
            #pragma unroll
            for (int r = 0; r < 4; ++r) s[nk][r] = sc[r];
        }
        // exp in C-layout -> Pbuf (f16), wave-private (no barrier)
        #pragma unroll
        for (int nk = 0; nk < 4; ++nk)
            #pragma unroll
            for (int r = 0; r < 4; ++r)
                Pbuf[wave][quad * 4 + r][nk * 16 + l16] = (_Float16)__expf(s[nk][r] * 0.125f);
        // A-frag read (q = l16, m contiguous), fold g multiplicatively
        f16x8 ep0 = *(const f16x8*)&Pbuf[wave][l16][quad * 8];
        f16x8 ep1 = *(const f16x8*)&Pbuf[wave][l16][32 + quad * 8];
        f16x8 g0 = *(const f16x8*)(Gq + kt * 64 + quad * 8);
        f16x8 g1 = *(const f16x8*)(Gq + kt * 64 + 32 + quad * 8);
        f16x8 gp0 = ep0 * g0;      // v_pk_mul_f16
        f16x8 gp1 = ep1 * g1;
        float part = 0.f;
        #pragma unroll
        for (int j = 0; j < 8; ++j) part += (float)gp0[j] + (float)gp1[j];
        rs += part;
        // PV (f16 MFMA)
        #pragma unroll
        for (int n4 = 0; n4 < 4; ++n4) {
            const long voff = ((long)(b * 1024 + h * 64 + n4 * 16 + l16)) * 512 + kt * 64 + quad * 8;
            f16x8 bv0 = *(const f16x8*)(Vt + voff);
            f16x8 bv1 = *(const f16x8*)(Vt + voff + 32);
            oacc[n4] = __builtin_amdgcn_mfma_f32_16x16x32_f16(gp0, bv0, oacc[n4], 0, 0, 0);
            oacc[n4] = __builtin_amdgcn_mfma_f32_16x16x32_f16(gp1, bv1, oacc[n4], 0, 0, 0);
        }
    }

    // reduce rs over the 4 quad-partners holding the same q = l16
    rs += __shfl_xor(rs, 16);
    rs += __shfl_xor(rs, 32);
    // redistribute to C-layout rows q = quad*4 + r
    float li[4];
    #pragma unroll
    for (int r = 0; r < 4; ++r) li[r] = __shfl(rs, quad * 4 + r);

    #pragma unroll
    for (int n4 = 0; n4 < 4; ++n4)
        #pragma unroll
        for (int r = 0; r < 4; ++r) {
            float o = oacc[n4][r] / li[r];
            O[((long)(b * 512 + qrow + quad * 4 + r)) * 1024 + h * 64 + n4 * 16 + l16] = f2bf(o);
        }
}

// ---------- launch ----------
extern "C" void kernel_launch(void* const* d_in, const int* in_sizes, int n_in,
                              void* d_out, int out_size, void* d_ws, size_t ws_size,
                              hipStream_t stream) {
    const float* queries = (const float*)d_in[0];
    const float* keys    = (const float*)d_in[1];
    const float* values  = (const float*)d_in[2];
    const float* boxes   = (const float*)d_in[3];
    const float* bq = (const float*)d_in[5];
    const float* bk = (const float*)d_in[7];
    const float* bv = (const float*)d_in[9];
    const float* bo = (const float*)d_in[11];
    const float* Wg = (const float*)d_in[12];
    const float* bg = (const float*)d_in[13];

    char* ws = (char*)d_ws;
    short* qbf = (short*)(ws + 0);           // [8192][1024] rows: queries then keys
    short* kbf = (short*)(ws + 8388608);
    short* vbf = (short*)(ws + 16777216);
    short* wqb = (short*)(ws + 25165824);    // wqb/wkb adjacent (z-stride 1048576 elems)
    short* wkb = (short*)(ws + 27262976);
    short* wvb = (short*)(ws + 29360128);
    short* wob = (short*)(ws + 31457280);
    short* Qh  = (short*)(ws + 33554432);    // Qh/Kh adjacent (z-stride 4194304 elems)
    short* Kh  = (short*)(ws + 41943040);
    _Float16* Vt = (_Float16*)(ws + 50331648);  // [b][1024 out][512 tok] f16
    short* Hd  = (short*)(ws + 58720256);    // hidden [4096][1024]
    __half* G  = (__half*)(ws + 67108864);   // g [b][h][512][512] f16, 67 MB
    _Float16* Wgh = (_Float16*)(ws + 33554432);  // overlaps Qh (dead before QK-proj)

    convert_qkv<<<dim3(4096, 3), 256, 0, stream>>>(queries, keys, values, qbf, kbf, vbf);
    convert_w4<<<dim3(1024, 4), 256, 0, stream>>>((const float*)d_in[4], (const float*)d_in[6],
                                                  (const float*)d_in[8], (const float*)d_in[10],
                                                  wqb, wkb, wvb, wob);
    convert_f32_f16<<<4, 256, 0, stream>>>(Wg, Wgh, 1024);

    geom_kernel2<<<dim3(8, 512, 8), 256, 0, stream>>>(boxes, Wgh, bg, G);

    // merged Q+K projection: z=0 -> queries@Wq -> Qh, z=1 -> keys@Wk -> Kh (512 blocks)
    gemm_lds<0, false><<<dim3(8, 32, 2), 256, 0, stream>>>(
        qbf, 4194304, wqb, 1048576, bq, bk, Qh, 4194304, 1024, 1024);
    // V projection (transposed output, f16): C[out][tok] per batch
    gemm_lds<2, true><<<dim3(4, 8, 8), 256, 0, stream>>>(
        wvb, 0, vbf, (long)512 * 1024, bv, bv, Vt, (long)1024 * 512, 1024, 512);

    flash_attn3<<<dim3(8, 16, 8), 256, 0, stream>>>(Qh, Kh, Vt, G, Hd);

    // output projection -> f32
    gemm_lds<1, false><<<dim3(8, 32, 1), 256, 0, stream>>>(
        Hd, 0, wob, 0, bo, bo, d_out, 0, 1024, 1024);
}